// Round 1
// baseline (551.065 us; speedup 1.0000x reference)
//
#include <hip/hip_runtime.h>

// Flow-warp bilinear resample with TF safe-gather + OOB masking.
// B=16, H=768, W=1024, C=4 (C=4 floats -> one float4 per pixel).
//
// Semantics (match JAX reference exactly):
//   warp_y = y + flow[...,0]; warp_x = x + flow[...,1]
//   x0=floor(wx), x1=ceil(wx)  (ceil, NOT x0+1 -- integer coords on the edge)
//   output = bilinear(taps) * mask, mask = all(0 <= warp <= dim-1)
// Inside the mask, floor/ceil taps are always in-bounds, so the safe-gather
// validity test reduces to the single mask branch; masked pixels are exact 0.

__global__ __launch_bounds__(256) void warp_bilinear_kernel(
    const float* __restrict__ src,   // [B,H,W,4]
    const float* __restrict__ flow,  // [B,H,W,2]
    float* __restrict__ out,         // [B,H,W,4]
    int B, int H, int W)
{
    int idx = blockIdx.x * blockDim.x + threadIdx.x;
    int total = B * H * W;
    if (idx >= total) return;

    int x  = idx % W;
    int hw = idx / W;
    int y  = hw % H;
    int b  = hw / H;

    // flow: channel 0 -> y displacement, channel 1 -> x displacement
    float2 fl = ((const float2*)flow)[idx];
    float wy = (float)y + fl.x;
    float wx = (float)x + fl.y;

    float4 result = make_float4(0.f, 0.f, 0.f, 0.f);

    bool valid = (wy >= 0.f) & (wy <= (float)(H - 1)) &
                 (wx >= 0.f) & (wx <= (float)(W - 1));
    if (valid) {
        float fx = floorf(wx);
        float fy = floorf(wy);
        int x0 = (int)fx;
        int y0 = (int)fy;
        int x1 = (int)ceilf(wx);
        int y1 = (int)ceilf(wy);
        float wr = wx - fx;          // w_right
        float wd = wy - fy;          // w_down
        float wl = 1.f - wr;         // w_left
        float wu = 1.f - wd;         // w_up

        const float4* s = (const float4*)src + (size_t)b * (H * W);
        float4 g00 = s[y0 * W + x0];
        float4 g01 = s[y0 * W + x1];
        float4 g10 = s[y1 * W + x0];
        float4 g11 = s[y1 * W + x1];

        result.x = (g00.x * wl + g01.x * wr) * wu + (g10.x * wl + g11.x * wr) * wd;
        result.y = (g00.y * wl + g01.y * wr) * wu + (g10.y * wl + g11.y * wr) * wd;
        result.z = (g00.z * wl + g01.z * wr) * wu + (g10.z * wl + g11.z * wr) * wd;
        result.w = (g00.w * wl + g01.w * wr) * wu + (g10.w * wl + g11.w * wr) * wd;
    }

    ((float4*)out)[idx] = result;
}

extern "C" void kernel_launch(void* const* d_in, const int* in_sizes, int n_in,
                              void* d_out, int out_size, void* d_ws, size_t ws_size,
                              hipStream_t stream) {
    const float* src  = (const float*)d_in[0];  // [B,H,W,4] fp32
    const float* flow = (const float*)d_in[1];  // [B,H,W,2] fp32
    float* out = (float*)d_out;

    const int B = 16, H = 768, W = 1024;
    int total = B * H * W;                       // 12,582,912 threads
    int block = 256;
    int grid = (total + block - 1) / block;      // 49,152 blocks

    warp_bilinear_kernel<<<grid, block, 0, stream>>>(src, flow, out, B, H, W);
}